// Round 6
// baseline (220.463 us; speedup 1.0000x reference)
//
#include <hip/hip_runtime.h>
#include <math.h>
#include <stdint.h>

#define NROWS 1024
#define DCAT  16384
#define NNEG  48
#define CAP   512
#define PCAP  16
// Candidate threshold on the 32-bit threefry output:
// rank = bits>>9 >= 2^23-98304  <=>  bits >= 0xFD000000.
// P(pass)=1.17%, E[cands/row]~192, sd~13.8 -> P(<48) ~ P(>512) ~ 0.
#define BITS_THR 0xFD000000u

typedef unsigned long long ull;

// ws layout (4.27 MB total):
//   [0)      poscnt[1024]  u32
//   [4096)   candcnt[1024] u32
//   [8192)   poscols[1024][16] i32
//   [73728)  ckeys[1024][512]  u64
#define WS_POSCNT(ws)  ((uint32_t*)(ws))
#define WS_CANDCNT(ws) ((uint32_t*)((char*)(ws) + 4096))
#define WS_POSCOL(ws)  ((int*)((char*)(ws) + 8192))
#define WS_CKEYS(ws)   ((ull*)((char*)(ws) + 73728))

// JAX threefry2x32, key=(0,42), counter=(0,idx), out = x0^x1
// (jax_threefry_partitionable 32-bit path). Verified exact (absmax=0).
// 4 independent chains interleaved for ILP; rotate -> v_alignbit_b32.
__device__ __forceinline__ void tf_bits4(uint32_t i0, uint32_t out[4]) {
  const uint32_t ks1 = 42u, ks2 = 0x1BD11BF0u; // 0x1BD11BDA^0^42, ks0=0
  uint32_t x0[4], x1[4];
  #pragma unroll
  for (int l = 0; l < 4; ++l) { x0[l] = 0u; x1[l] = i0 + (uint32_t)l + ks1; }
#define QR(rot) \
  _Pragma("unroll") \
  for (int l = 0; l < 4; ++l) { \
    x0[l] += x1[l]; x1[l] = __builtin_rotateleft32(x1[l], (rot)); x1[l] ^= x0[l]; }
#define INJ(a, b) \
  _Pragma("unroll") \
  for (int l = 0; l < 4; ++l) { x0[l] += (a); x1[l] += (b); }
  QR(13) QR(15) QR(26) QR(6)  INJ(ks1, ks2 + 1u)
  QR(17) QR(29) QR(16) QR(24) INJ(ks2, 2u)
  QR(13) QR(15) QR(26) QR(6)  INJ(0u,  ks1 + 3u)
  QR(17) QR(29) QR(16) QR(24) INJ(ks1, ks2 + 4u)
  QR(13) QR(15) QR(26) QR(6)  INJ(ks2, 5u)
#undef QR
#undef INJ
  #pragma unroll
  for (int l = 0; l < 4; ++l) out[l] = x0[l] ^ x1[l];
}

// jax.nn.softplus = max(x,0) + log1p(exp(-|x|))
__device__ __forceinline__ float softplus_(float x) {
  return fmaxf(x, 0.f) + log1pf(expf(-fabsf(x)));
}

// ---- Kernel A: straight-line scan. 16384 blocks x 256 thr, 4 elems/thread.
// No loop, no barrier, no LDS. Rare pushes to global per-row lists.
__global__ __launch_bounds__(256) void scan_kernel(
    const float* __restrict__ target, void* __restrict__ ws) {
  const uint32_t gidx = ((uint32_t)blockIdx.x << 10) | ((uint32_t)threadIdx.x << 2);
  const int row = gidx >> 14;
  const float4 tv = *reinterpret_cast<const float4*>(target + gidx);
  uint32_t bits[4];
  tf_bits4(gidx, bits);

  // positives (~0.05% of lanes take this)
  const uint32_t pm = __float_as_uint(tv.x) | __float_as_uint(tv.y) |
                      __float_as_uint(tv.z) | __float_as_uint(tv.w);
  if (pm) {
    const float v[4] = {tv.x, tv.y, tv.z, tv.w};
    #pragma unroll
    for (int j = 0; j < 4; ++j)
      if (v[j] > 0.f) {
        const uint32_t p = atomicAdd(WS_POSCNT(ws) + row, 1u);
        if (p < PCAP) WS_POSCOL(ws)[row * PCAP + p] = (int)(gidx & 0x3FFFu) + j;
      }
  }
  // candidates (~1.2% of lanes; positivity filtered in kernel B)
  #pragma unroll
  for (int j = 0; j < 4; ++j)
    if (bits[j] >= BITS_THR) {
      const uint32_t p = atomicAdd(WS_CANDCNT(ws) + row, 1u);
      if (p < CAP)
        // key: (rank desc, col asc) via one u64 compare; unique per row
        WS_CKEYS(ws)[row * CAP + p] =
            ((ull)(bits[j] >> 9) << 14) |
            (ull)(DCAT - 1 - ((int)(gidx & 0x3FFFu) + j));
    }
}

// ---- Kernel B: per-row selection + loss. 1024 blocks x 256 thr.
__global__ __launch_bounds__(256) void select_kernel(
    const float* __restrict__ pred, const void* __restrict__ ws,
    float* __restrict__ out) {
  const int row = blockIdx.x;
  const int tid = threadIdx.x;
  const float* __restrict__ prow = pred + (size_t)row * DCAT;

  __shared__ ull k_s[CAP];
  __shared__ int pc_s[PCAP];
  __shared__ float wsum[4];

  const int M = min((int)WS_CANDCNT(ws)[row], CAP);
  const int PN = min((int)WS_POSCNT(ws)[row], PCAP);
  for (int i = tid; i < M; i += 256) k_s[i] = WS_CKEYS(ws)[row * CAP + i];
  if (tid < PCAP) pc_s[tid] = (tid < PN) ? WS_POSCOL(ws)[row * PCAP + tid] : -1;
  __syncthreads();

  // invalidate contaminated candidates (high-rank positives)
  for (int i = tid; i < M; i += 256) {
    const int col = DCAT - 1 - (int)(k_s[i] & 0x3FFFull);
    bool hit = false;
    #pragma unroll
    for (int j = 0; j < PCAP; ++j) hit |= (col == pc_s[j]);
    if (hit) k_s[i] = 0ull;
  }
  __syncthreads();

  float acc = 0.f;
  // exact top-48 by rank-counting (O(M^2), broadcast LDS reads,
  // order-independent -> deterministic)
  for (int i = tid; i < M; i += 256) {
    const ull mine = k_s[i];
    if (mine) {
      int higher = 0;
      for (int j = 0; j < M; ++j) higher += (k_s[j] > mine) ? 1 : 0;
      if (higher < NNEG) {
        const int col = DCAT - 1 - (int)(mine & 0x3FFFull);
        acc += softplus_(prow[col]);      // negative term: softplus(x)
      }
    }
  }
  if (tid < PN) acc += softplus_(-prow[pc_s[tid]]);  // positive term

  for (int off = 32; off > 0; off >>= 1) acc += __shfl_down(acc, off, 64);
  if ((tid & 63) == 0) wsum[tid >> 6] = acc;
  __syncthreads();
  if (tid == 0) atomicAdd(out, wsum[0] + wsum[1] + wsum[2] + wsum[3]);
}

extern "C" void kernel_launch(void* const* d_in, const int* in_sizes, int n_in,
                              void* d_out, int out_size, void* d_ws, size_t ws_size,
                              hipStream_t stream) {
  const float* pred   = (const float*)d_in[0];
  const float* target = (const float*)d_in[1];
  // d_in[2] = k (int scalar) — compile-time constant 8 in this problem.
  float* out = (float*)d_out;
  hipMemsetAsync(d_ws, 0, 8192, stream);              // pos/cand counters
  hipMemsetAsync(out, 0, sizeof(float), stream);
  scan_kernel<<<dim3(NROWS * 16), dim3(256), 0, stream>>>(target, d_ws);
  select_kernel<<<dim3(NROWS), dim3(256), 0, stream>>>(pred, d_ws, out);
}

// Round 7
// 57.095 us; speedup vs baseline: 3.8613x; 3.8613x over previous
//
#include <hip/hip_runtime.h>
#include <math.h>
#include <stdint.h>

#define NROWS 1024
#define DCAT  16384
#define BLK   512
#define NNEG  48
#define CAP   512
// Candidate threshold on the 32-bit threefry output:
// rank = bits>>9 >= 2^23-98304  <=>  bits >= 0xFD000000.
// P(pass)=1.17%, E[cands/row]~192, sd~13.8 -> P(<48) ~ P(>512) ~ 0.
#define BITS_THR 0xFD000000u
#define POSBIT   (1ull << 37)

typedef unsigned long long ull;

// ---- Inline-asm threefry2x32, key=(0,42), counter=(0,idx), out=x0^x1.
// (jax_threefry_partitionable 32-bit path; C version verified absmax=0.)
// 4 chains interleaved; exactly 3 VALU per QR round via v_alignbit_b32
// (rotl(x,r) == alignbit(x,x,32-r)). Injection adds: 42/45/2/5 are inline
// consts; 0x1BD11BF? are VOP2 src0 literals (legal).
// Round shifts: rot{13,15,26,6}->sh{19,17,6,26}; rot{17,29,16,24}->sh{15,3,16,8}.
#define TFR(X0, X1, SH) \
  "v_add_u32 " X0 ", " X0 ", " X1 "\n\t" \
  "v_alignbit_b32 " X1 ", " X1 ", " X1 ", " SH "\n\t" \
  "v_xor_b32 " X1 ", " X1 ", " X0 "\n\t"
#define R4X(SH) TFR("%0","%1",SH) TFR("%2","%3",SH) TFR("%4","%5",SH) TFR("%6","%7",SH)
#define I4(K0, K1) \
  "v_add_u32 %0, " K0 ", %0\n\t" "v_add_u32 %1, " K1 ", %1\n\t" \
  "v_add_u32 %2, " K0 ", %2\n\t" "v_add_u32 %3, " K1 ", %3\n\t" \
  "v_add_u32 %4, " K0 ", %4\n\t" "v_add_u32 %5, " K1 ", %5\n\t" \
  "v_add_u32 %6, " K0 ", %6\n\t" "v_add_u32 %7, " K1 ", %7\n\t"
#define I4B(K1) \
  "v_add_u32 %1, " K1 ", %1\n\t" "v_add_u32 %3, " K1 ", %3\n\t" \
  "v_add_u32 %5, " K1 ", %5\n\t" "v_add_u32 %7, " K1 ", %7\n\t"

__device__ __forceinline__ void tf_bits4_asm(uint32_t i0, uint32_t out[4]) {
  uint32_t a0 = 0u, a1 = i0 + 42u;
  uint32_t b0 = 0u, b1 = i0 + 43u;
  uint32_t c0 = 0u, c1 = i0 + 44u;
  uint32_t d0 = 0u, d1 = i0 + 45u;
  asm(R4X("19") R4X("17") R4X("6")  R4X("26") I4("42", "0x1BD11BF1")
      R4X("15") R4X("3")  R4X("16") R4X("8")  I4("0x1BD11BF0", "2")
      R4X("19") R4X("17") R4X("6")  R4X("26") I4B("45")
      R4X("15") R4X("3")  R4X("16") R4X("8")  I4("42", "0x1BD11BF4")
      R4X("19") R4X("17") R4X("6")  R4X("26") I4("0x1BD11BF0", "5")
      : "+v"(a0), "+v"(a1), "+v"(b0), "+v"(b1),
        "+v"(c0), "+v"(c1), "+v"(d0), "+v"(d1));
  out[0] = a0 ^ a1; out[1] = b0 ^ b1; out[2] = c0 ^ c1; out[3] = d0 ^ d1;
}

// jax.nn.softplus = max(x,0) + log1p(exp(-|x|))
__device__ __forceinline__ float softplus_(float x) {
  return fmaxf(x, 0.f) + log1pf(expf(-fabsf(x)));
}

__global__ __launch_bounds__(BLK, 8) void t2l2_kernel(
    const float* __restrict__ pred, const float* __restrict__ target,
    float* __restrict__ out) {
  const int row = blockIdx.x;
  const int tid = threadIdx.x;
  const float* __restrict__ trow = target + (size_t)row * DCAT;
  const float* __restrict__ prow = pred + (size_t)row * DCAT;
  const float4* __restrict__ t4p = reinterpret_cast<const float4*>(trow);

  __shared__ ull ckeys[CAP];
  __shared__ int cnt_s;
  __shared__ float wsum[BLK / 64];
  if (tid == 0) cnt_s = 0;
  __syncthreads();

  float acc = 0.f;
  const uint32_t base = (uint32_t)row * (uint32_t)DCAT;

  // Phase 1: per iter, one float4 target load (issued before the ~284-instr
  // asm block that hides its latency) + 4-chain asm threefry + one rare
  // merged branch per element pushing {positive | high-rank cand} to LDS.
  for (int it = 0; it < DCAT / (BLK * 4); ++it) {   // 8 iters, not unrolled
    const int c4 = it * BLK + tid;
    const float4 tv4 = t4p[c4];                     // cols 4*c4 .. 4*c4+3
    uint32_t bits[4];
    tf_bits4_asm(base + (uint32_t)(c4 << 2), bits);
    const float tv[4] = {tv4.x, tv4.y, tv4.z, tv4.w};
    #pragma unroll
    for (int j = 0; j < 4; ++j) {
      const bool pos = tv[j] > 0.f;                 // ~0.05% of lanes
      if (pos | (bits[j] >= BITS_THR)) {            // wave-taken ~54%/elem
        const int col = (c4 << 2) + j;
        ull key = ((ull)(bits[j] >> 9) << 14)
                | (ull)(DCAT - 1 - col);            // (rank desc, col asc)
        if (pos) key |= POSBIT;                     // positives sort on top
        const int p = atomicAdd(&cnt_s, 1);
        if (p < CAP) ckeys[p] = key;
      }
    }
  }
  __syncthreads();

  // Phase 2: positives -> softplus(-x); negatives -> exact top-48 among
  // negative keys by rank-counting (O(M^2), broadcast LDS reads,
  // order-independent). All pred gathers happen here (~56/row).
  const int M = min(cnt_s, CAP);
  for (int i = tid; i < M; i += BLK) {
    const ull mine = ckeys[i];
    const int col = DCAT - 1 - (int)(mine & 0x3FFFull);
    if (mine & POSBIT) {
      acc += softplus_(-prow[col]);       // positive term: softplus(-x)
    } else {
      int higher = 0;
      for (int j = 0; j < M; ++j) {
        const ull kj = ckeys[j];
        higher += (kj > mine && kj < POSBIT) ? 1 : 0;  // negatives only
      }
      if (higher < NNEG)
        acc += softplus_(prow[col]);      // negative term: softplus(x)
    }
  }

  // Block reduction -> one atomic per block.
  for (int off = 32; off > 0; off >>= 1) acc += __shfl_down(acc, off, 64);
  if ((tid & 63) == 0) wsum[tid >> 6] = acc;
  __syncthreads();
  if (tid == 0) {
    float s = 0.f;
    #pragma unroll
    for (int w = 0; w < BLK / 64; ++w) s += wsum[w];
    atomicAdd(out, s);
  }
}

extern "C" void kernel_launch(void* const* d_in, const int* in_sizes, int n_in,
                              void* d_out, int out_size, void* d_ws, size_t ws_size,
                              hipStream_t stream) {
  const float* pred   = (const float*)d_in[0];
  const float* target = (const float*)d_in[1];
  // d_in[2] = k (int scalar) — compile-time constant 8 in this problem.
  float* out = (float*)d_out;
  hipMemsetAsync(out, 0, sizeof(float), stream);
  t2l2_kernel<<<dim3(NROWS), dim3(BLK), 0, stream>>>(pred, target, out);
}

// Round 8
// 55.427 us; speedup vs baseline: 3.9775x; 1.0301x over previous
//
#include <hip/hip_runtime.h>
#include <math.h>
#include <stdint.h>

#define NROWS 1024
#define DCAT  16384
#define BLK   512
#define NNEG  48
#define CAP   512
// Candidate threshold on the 32-bit threefry output:
// rank = bits>>9 >= 2^23-98304  <=>  bits >= 0xFD000000.
// P(pass)=1.17%, E[cands/row]~192, sd~13.8 -> P(<48) ~ P(>512) ~ 0.
#define BITS_THR 0xFD000000u
#define POSBIT   (1ull << 37)

typedef unsigned long long ull;

// ---- Inline-asm threefry2x32, key=(0,42), counter=(0,idx), out=x0^x1
// (jax_threefry_partitionable 32-bit path; verified absmax=0 in R4/R7).
// 8 chains, OPERATION-INTERLEAVED: 8 adds, then 8 rotates, then 8 xors per
// round -> 7 independent instrs between every dependent pair; dependency
// latency hidden within a single wave regardless of occupancy.
// rotl(x,r) == v_alignbit_b32(x,x,32-r).
// x0 chains: %0-%7, x1 chains: %8-%15; SGPR consts: %16/%17/%18.
#define ADD8 \
  "v_add_u32 %0, %0, %8\n\t"   "v_add_u32 %1, %1, %9\n\t" \
  "v_add_u32 %2, %2, %10\n\t"  "v_add_u32 %3, %3, %11\n\t" \
  "v_add_u32 %4, %4, %12\n\t"  "v_add_u32 %5, %5, %13\n\t" \
  "v_add_u32 %6, %6, %14\n\t"  "v_add_u32 %7, %7, %15\n\t"
#define ROT8(SH) \
  "v_alignbit_b32 %8, %8, %8, " SH "\n\t"   "v_alignbit_b32 %9, %9, %9, " SH "\n\t" \
  "v_alignbit_b32 %10, %10, %10, " SH "\n\t" "v_alignbit_b32 %11, %11, %11, " SH "\n\t" \
  "v_alignbit_b32 %12, %12, %12, " SH "\n\t" "v_alignbit_b32 %13, %13, %13, " SH "\n\t" \
  "v_alignbit_b32 %14, %14, %14, " SH "\n\t" "v_alignbit_b32 %15, %15, %15, " SH "\n\t"
#define XOR8 \
  "v_xor_b32 %8, %8, %0\n\t"   "v_xor_b32 %9, %9, %1\n\t" \
  "v_xor_b32 %10, %10, %2\n\t" "v_xor_b32 %11, %11, %3\n\t" \
  "v_xor_b32 %12, %12, %4\n\t" "v_xor_b32 %13, %13, %5\n\t" \
  "v_xor_b32 %14, %14, %6\n\t" "v_xor_b32 %15, %15, %7\n\t"
#define QR8(SH) ADD8 ROT8(SH) XOR8
// Injection adds: src0 = inline const or SGPR (both 4-byte encodings).
#define INJ0(K) \
  "v_add_u32 %0, " K ", %0\n\t" "v_add_u32 %1, " K ", %1\n\t" \
  "v_add_u32 %2, " K ", %2\n\t" "v_add_u32 %3, " K ", %3\n\t" \
  "v_add_u32 %4, " K ", %4\n\t" "v_add_u32 %5, " K ", %5\n\t" \
  "v_add_u32 %6, " K ", %6\n\t" "v_add_u32 %7, " K ", %7\n\t"
#define INJ1(K) \
  "v_add_u32 %8, " K ", %8\n\t"  "v_add_u32 %9, " K ", %9\n\t" \
  "v_add_u32 %10, " K ", %10\n\t" "v_add_u32 %11, " K ", %11\n\t" \
  "v_add_u32 %12, " K ", %12\n\t" "v_add_u32 %13, " K ", %13\n\t" \
  "v_add_u32 %14, " K ", %14\n\t" "v_add_u32 %15, " K ", %15\n\t"

__device__ __forceinline__ void tf_bits8_asm(uint32_t i0, uint32_t out[8]) {
  uint32_t x00 = 0, x01 = 0, x02 = 0, x03 = 0, x04 = 0, x05 = 0, x06 = 0, x07 = 0;
  uint32_t x10 = i0 + 42u, x11 = i0 + 43u, x12 = i0 + 44u, x13 = i0 + 45u;
  uint32_t x14 = i0 + 46u, x15 = i0 + 47u, x16 = i0 + 48u, x17 = i0 + 49u;
  const uint32_t kA = 0x1BD11BF0u, kB = 0x1BD11BF1u, kC = 0x1BD11BF4u;
  // rot{13,15,26,6}->sh{19,17,6,26}; rot{17,29,16,24}->sh{15,3,16,8}
  asm(QR8("19") QR8("17") QR8("6")  QR8("26") INJ0("42")   INJ1("%17")
      QR8("15") QR8("3")  QR8("16") QR8("8")  INJ0("%16")  INJ1("2")
      QR8("19") QR8("17") QR8("6")  QR8("26")              INJ1("45")
      QR8("15") QR8("3")  QR8("16") QR8("8")  INJ0("42")   INJ1("%18")
      QR8("19") QR8("17") QR8("6")  QR8("26") INJ0("%16")  INJ1("5")
      : "+v"(x00), "+v"(x01), "+v"(x02), "+v"(x03),
        "+v"(x04), "+v"(x05), "+v"(x06), "+v"(x07),
        "+v"(x10), "+v"(x11), "+v"(x12), "+v"(x13),
        "+v"(x14), "+v"(x15), "+v"(x16), "+v"(x17)
      : "s"(kA), "s"(kB), "s"(kC));
  out[0] = x00 ^ x10; out[1] = x01 ^ x11; out[2] = x02 ^ x12; out[3] = x03 ^ x13;
  out[4] = x04 ^ x14; out[5] = x05 ^ x15; out[6] = x06 ^ x16; out[7] = x07 ^ x17;
}

// jax.nn.softplus = max(x,0) + log1p(exp(-|x|))
__device__ __forceinline__ float softplus_(float x) {
  return fmaxf(x, 0.f) + log1pf(expf(-fabsf(x)));
}

__global__ __launch_bounds__(BLK, 8) void t2l2_kernel(
    const float* __restrict__ pred, const float* __restrict__ target,
    float* __restrict__ out) {
  const int row = blockIdx.x;
  const int tid = threadIdx.x;
  const float* __restrict__ trow = target + (size_t)row * DCAT;
  const float* __restrict__ prow = pred + (size_t)row * DCAT;
  const float4* __restrict__ t4p = reinterpret_cast<const float4*>(trow);

  __shared__ ull ckeys[CAP];
  __shared__ int cnt_s;
  __shared__ float wsum[BLK / 64];
  if (tid == 0) cnt_s = 0;
  __syncthreads();

  float acc = 0.f;
  const uint32_t base = (uint32_t)row * (uint32_t)DCAT;

  // Phase 1: per iter, two float4 target loads (issued before the ~552-instr
  // asm block hides their latency) + 8-chain interleaved asm threefry + one
  // rare merged branch per element pushing {pos | high-rank cand} to LDS.
  for (int it = 0; it < DCAT / (BLK * 8); ++it) {   // 4 iters
    const int e0 = it * (BLK * 8) + tid * 8;        // 8 consecutive elems
    const float4 a0 = t4p[e0 / 4];
    const float4 a1 = t4p[e0 / 4 + 1];
    uint32_t bits[8];
    tf_bits8_asm(base + (uint32_t)e0, bits);
    const float tv[8] = {a0.x, a0.y, a0.z, a0.w, a1.x, a1.y, a1.z, a1.w};
    #pragma unroll
    for (int j = 0; j < 8; ++j) {
      const bool pos = tv[j] > 0.f;                 // ~0.05% of lanes
      if (pos | (bits[j] >= BITS_THR)) {            // rare per-lane
        const int col = e0 + j;
        ull key = ((ull)(bits[j] >> 9) << 14)
                | (ull)(DCAT - 1 - col);            // (rank desc, col asc)
        if (pos) key |= POSBIT;                     // positives sort on top
        const int p = atomicAdd(&cnt_s, 1);
        if (p < CAP) ckeys[p] = key;
      }
    }
  }
  __syncthreads();

  // Phase 2: positives -> softplus(-x); negatives -> exact top-48 among
  // negative keys by rank-counting (O(M^2), broadcast LDS reads,
  // order-independent). All pred gathers happen here (~56/row).
  const int M = min(cnt_s, CAP);
  for (int i = tid; i < M; i += BLK) {
    const ull mine = ckeys[i];
    const int col = DCAT - 1 - (int)(mine & 0x3FFFull);
    if (mine & POSBIT) {
      acc += softplus_(-prow[col]);       // positive term: softplus(-x)
    } else {
      int higher = 0;
      for (int j = 0; j < M; ++j) {
        const ull kj = ckeys[j];
        higher += (kj > mine && kj < POSBIT) ? 1 : 0;  // negatives only
      }
      if (higher < NNEG)
        acc += softplus_(prow[col]);      // negative term: softplus(x)
    }
  }

  // Block reduction -> one atomic per block.
  for (int off = 32; off > 0; off >>= 1) acc += __shfl_down(acc, off, 64);
  if ((tid & 63) == 0) wsum[tid >> 6] = acc;
  __syncthreads();
  if (tid == 0) {
    float s = 0.f;
    #pragma unroll
    for (int w = 0; w < BLK / 64; ++w) s += wsum[w];
    atomicAdd(out, s);
  }
}

extern "C" void kernel_launch(void* const* d_in, const int* in_sizes, int n_in,
                              void* d_out, int out_size, void* d_ws, size_t ws_size,
                              hipStream_t stream) {
  const float* pred   = (const float*)d_in[0];
  const float* target = (const float*)d_in[1];
  // d_in[2] = k (int scalar) — compile-time constant 8 in this problem.
  float* out = (float*)d_out;
  hipMemsetAsync(out, 0, sizeof(float), stream);
  t2l2_kernel<<<dim3(NROWS), dim3(BLK), 0, stream>>>(pred, target, out);
}

// Round 9
// 52.474 us; speedup vs baseline: 4.2014x; 1.0563x over previous
//
#include <hip/hip_runtime.h>
#include <math.h>
#include <stdint.h>

#define NROWS 1024
#define DCAT  16384
#define BLK   512
#define NNEG  48
#define PCAP  16
#define WCAP  64    // per-wave candidate cap: lambda=24, P(overflow)~e^-108
// Candidate threshold on the 32-bit threefry output:
// rank = bits>>9 >= 2^23-98304  <=>  bits >= 0xFD000000. P(pass)=1.17%.
#define BITS_THR 0xFD000000u

typedef unsigned long long ull;

// ---- Inline-asm threefry2x32, key=(0,42), counter=(0,idx), out=x0^x1
// (jax_threefry_partitionable 32-bit path; R7/R8 verified absmax=0).
// 8 chains operation-interleaved. Trims vs R8: round-1 ADD elided via
// x0:=x1init; injections 1/2/4 fused into the next round's add via
// v_add3_u32; final xor inside asm (result lands in x1 regs %8-%15).
// x0: %0-%7, x1: %8-%15. SGPRs: %16=0x1BD11BF0 %17=0x1BD11BF1 %18=0x1BD11BF4.
#define ADD8 \
  "v_add_u32 %0, %0, %8\n\t"   "v_add_u32 %1, %1, %9\n\t" \
  "v_add_u32 %2, %2, %10\n\t"  "v_add_u32 %3, %3, %11\n\t" \
  "v_add_u32 %4, %4, %12\n\t"  "v_add_u32 %5, %5, %13\n\t" \
  "v_add_u32 %6, %6, %14\n\t"  "v_add_u32 %7, %7, %15\n\t"
#define ADD8_3(K) \
  "v_add3_u32 %0, %0, %8, " K "\n\t"   "v_add3_u32 %1, %1, %9, " K "\n\t" \
  "v_add3_u32 %2, %2, %10, " K "\n\t"  "v_add3_u32 %3, %3, %11, " K "\n\t" \
  "v_add3_u32 %4, %4, %12, " K "\n\t"  "v_add3_u32 %5, %5, %13, " K "\n\t" \
  "v_add3_u32 %6, %6, %14, " K "\n\t"  "v_add3_u32 %7, %7, %15, " K "\n\t"
#define ROT8(SH) \
  "v_alignbit_b32 %8, %8, %8, " SH "\n\t"   "v_alignbit_b32 %9, %9, %9, " SH "\n\t" \
  "v_alignbit_b32 %10, %10, %10, " SH "\n\t" "v_alignbit_b32 %11, %11, %11, " SH "\n\t" \
  "v_alignbit_b32 %12, %12, %12, " SH "\n\t" "v_alignbit_b32 %13, %13, %13, " SH "\n\t" \
  "v_alignbit_b32 %14, %14, %14, " SH "\n\t" "v_alignbit_b32 %15, %15, %15, " SH "\n\t"
#define XOR8 \
  "v_xor_b32 %8, %8, %0\n\t"   "v_xor_b32 %9, %9, %1\n\t" \
  "v_xor_b32 %10, %10, %2\n\t" "v_xor_b32 %11, %11, %3\n\t" \
  "v_xor_b32 %12, %12, %4\n\t" "v_xor_b32 %13, %13, %5\n\t" \
  "v_xor_b32 %14, %14, %6\n\t" "v_xor_b32 %15, %15, %7\n\t"
#define INJ1(K) \
  "v_add_u32 %8, " K ", %8\n\t"  "v_add_u32 %9, " K ", %9\n\t" \
  "v_add_u32 %10, " K ", %10\n\t" "v_add_u32 %11, " K ", %11\n\t" \
  "v_add_u32 %12, " K ", %12\n\t" "v_add_u32 %13, " K ", %13\n\t" \
  "v_add_u32 %14, " K ", %14\n\t" "v_add_u32 %15, " K ", %15\n\t"
#define INJ0S \
  "v_add_u32 %0, %16, %0\n\t" "v_add_u32 %1, %16, %1\n\t" \
  "v_add_u32 %2, %16, %2\n\t" "v_add_u32 %3, %16, %3\n\t" \
  "v_add_u32 %4, %16, %4\n\t" "v_add_u32 %5, %16, %5\n\t" \
  "v_add_u32 %6, %16, %6\n\t" "v_add_u32 %7, %16, %7\n\t"

// jax.nn.softplus = max(x,0) + log1p(exp(-|x|))
__device__ __forceinline__ float softplus_(float x) {
  return fmaxf(x, 0.f) + log1pf(expf(-fabsf(x)));
}

__global__ __launch_bounds__(BLK, 8) void t2l2_kernel(
    const float* __restrict__ pred, const float* __restrict__ target,
    float* __restrict__ out) {
  const int row = blockIdx.x;
  const int tid = threadIdx.x;
  const int wid = tid >> 6, lane = tid & 63;
  const float* __restrict__ trow = target + (size_t)row * DCAT;
  const float* __restrict__ prow = pred + (size_t)row * DCAT;
  const float4* __restrict__ t4p = reinterpret_cast<const float4*>(trow);

  __shared__ ull wkeys[8][WCAP];      // per-wave private candidate lists
  __shared__ uint32_t wcnts_s[8];
  __shared__ ull dense[512];
  __shared__ int pos_s[PCAP];
  __shared__ int pcnt_s, M_s;
  __shared__ float wsum[8];
  if (tid < PCAP) pos_s[tid] = -1;
  if (tid == 0) pcnt_s = 0;
  __syncthreads();

  const uint32_t base = (uint32_t)row * (uint32_t)DCAT;

  // Preload ALL target data (8x float4/thread); latency hides under asm.
  const float4 pl0 = t4p[tid * 2],           pl1 = t4p[tid * 2 + 1];
  const float4 pl2 = t4p[BLK*2 + tid * 2],   pl3 = t4p[BLK*2 + tid * 2 + 1];
  const float4 pl4 = t4p[BLK*4 + tid * 2],   pl5 = t4p[BLK*4 + tid * 2 + 1];
  const float4 pl6 = t4p[BLK*6 + tid * 2],   pl7 = t4p[BLK*6 + tid * 2 + 1];

  const uint32_t kA = 0x1BD11BF0u, kB = 0x1BD11BF1u, kC = 0x1BD11BF4u;
  uint32_t wcnt = 0;

  // Phase 1: pure-ALU threefry (8 chains) + wave-private, atomic-free,
  // wait-free candidate push; target positives consumed between groups.
#define TF8_PUSH(IT, PA, PB)                                                   \
  {                                                                            \
    const int e0 = (IT) * (BLK * 8) + tid * 8;                                 \
    const uint32_t i0 = base + (uint32_t)e0;                                   \
    uint32_t x00=i0+42u,x01=i0+43u,x02=i0+44u,x03=i0+45u;                      \
    uint32_t x04=i0+46u,x05=i0+47u,x06=i0+48u,x07=i0+49u;                      \
    uint32_t x10=x00,x11=x01,x12=x02,x13=x03,x14=x04,x15=x05,x16=x06,x17=x07;  \
    asm(ROT8("19") XOR8                                                        \
        ADD8 ROT8("17") XOR8                                                   \
        ADD8 ROT8("6")  XOR8                                                   \
        ADD8 ROT8("26") XOR8 INJ1("%17")                                       \
        ADD8_3("42") ROT8("15") XOR8                                           \
        ADD8 ROT8("3")  XOR8                                                   \
        ADD8 ROT8("16") XOR8                                                   \
        ADD8 ROT8("8")  XOR8 INJ1("2")                                         \
        ADD8_3("%16") ROT8("19") XOR8                                          \
        ADD8 ROT8("17") XOR8                                                   \
        ADD8 ROT8("6")  XOR8                                                   \
        ADD8 ROT8("26") XOR8 INJ1("45")                                        \
        ADD8 ROT8("15") XOR8                                                   \
        ADD8 ROT8("3")  XOR8                                                   \
        ADD8 ROT8("16") XOR8                                                   \
        ADD8 ROT8("8")  XOR8 INJ1("%18")                                       \
        ADD8_3("42") ROT8("19") XOR8                                           \
        ADD8 ROT8("17") XOR8                                                   \
        ADD8 ROT8("6")  XOR8                                                   \
        ADD8 ROT8("26") XOR8 INJ0S INJ1("5") XOR8                              \
        : "+v"(x00),"+v"(x01),"+v"(x02),"+v"(x03),                             \
          "+v"(x04),"+v"(x05),"+v"(x06),"+v"(x07),                             \
          "+v"(x10),"+v"(x11),"+v"(x12),"+v"(x13),                             \
          "+v"(x14),"+v"(x15),"+v"(x16),"+v"(x17)                              \
        : "s"(kA), "s"(kB), "s"(kC));                                          \
    const uint32_t b[8] = {x10,x11,x12,x13,x14,x15,x16,x17};                   \
    _Pragma("unroll")                                                          \
    for (int j = 0; j < 8; ++j) {                                              \
      const ull m = __ballot(b[j] >= BITS_THR);                                \
      if (m) {                                                                 \
        const uint32_t pre = __builtin_amdgcn_mbcnt_hi(                        \
            (uint32_t)(m >> 32), __builtin_amdgcn_mbcnt_lo((uint32_t)m, 0));   \
        if (b[j] >= BITS_THR)                                                  \
          wkeys[wid][wcnt + pre] = ((ull)(b[j] >> 9) << 14)                    \
                                 | (ull)(DCAT - 1 - (e0 + j));                 \
        wcnt += (uint32_t)__popcll(m);                                         \
      }                                                                        \
    }                                                                          \
    const uint32_t sb = __float_as_uint((PA).x)|__float_as_uint((PA).y)|       \
                        __float_as_uint((PA).z)|__float_as_uint((PA).w)|       \
                        __float_as_uint((PB).x)|__float_as_uint((PB).y)|       \
                        __float_as_uint((PB).z)|__float_as_uint((PB).w);       \
    if (__ballot(sb != 0)) {                                                   \
      const float tv[8] = {(PA).x,(PA).y,(PA).z,(PA).w,                        \
                           (PB).x,(PB).y,(PB).z,(PB).w};                       \
      _Pragma("unroll")                                                        \
      for (int j = 0; j < 8; ++j)                                              \
        if (tv[j] > 0.f) {                                                     \
          const int p = atomicAdd(&pcnt_s, 1);                                 \
          if (p < PCAP) pos_s[p] = e0 + j;                                     \
        }                                                                      \
    }                                                                          \
  }

  TF8_PUSH(0, pl0, pl1)
  TF8_PUSH(1, pl2, pl3)
  TF8_PUSH(2, pl4, pl5)
  TF8_PUSH(3, pl6, pl7)
#undef TF8_PUSH

  if (lane == 0) wcnts_s[wid] = wcnt;
  __syncthreads();

  // Compact the 8 wave lists into dense[]; compute M.
  uint32_t off = 0;
  for (int w = 0; w < wid; ++w) off += wcnts_s[w];
  const uint32_t mycnt = wcnts_s[wid];
  for (uint32_t i = lane; i < mycnt; i += 64) dense[off + i] = wkeys[wid][i];
  if (tid == 0) {
    int t = 0;
    for (int w = 0; w < 8; ++w) t += wcnts_s[w];
    M_s = t;
  }
  __syncthreads();

  // Invalidate candidates at positive columns (noise masked there).
  const int M = M_s;
  for (int i = tid; i < M; i += BLK) {
    const int col = DCAT - 1 - (int)(dense[i] & 0x3FFFull);
    bool hit = false;
    #pragma unroll
    for (int q = 0; q < PCAP; ++q) hit |= (col == pos_s[q]);
    if (hit) dense[i] = 0ull;
  }
  __syncthreads();

  float acc = 0.f;
  // Exact top-48 by rank-counting (O(M^2), broadcast LDS reads,
  // order-independent -> deterministic) + negative loss.
  for (int i = tid; i < M; i += BLK) {
    const ull mine = dense[i];
    if (mine) {
      int higher = 0;
      for (int j = 0; j < M; ++j) higher += (dense[j] > mine) ? 1 : 0;
      if (higher < NNEG) {
        const int col = DCAT - 1 - (int)(mine & 0x3FFFull);
        acc += softplus_(prow[col]);      // negative term: softplus(x)
      }
    }
  }
  // Positive loss (exactly K=8 per row).
  if (tid < min(pcnt_s, PCAP)) acc += softplus_(-prow[pos_s[tid]]);

  // Block reduction -> one atomic per block.
  for (int o = 32; o > 0; o >>= 1) acc += __shfl_down(acc, o, 64);
  if (lane == 0) wsum[wid] = acc;
  __syncthreads();
  if (tid == 0) {
    float s = 0.f;
    #pragma unroll
    for (int w = 0; w < 8; ++w) s += wsum[w];
    atomicAdd(out, s);
  }
}

extern "C" void kernel_launch(void* const* d_in, const int* in_sizes, int n_in,
                              void* d_out, int out_size, void* d_ws, size_t ws_size,
                              hipStream_t stream) {
  const float* pred   = (const float*)d_in[0];
  const float* target = (const float*)d_in[1];
  // d_in[2] = k (int scalar) — compile-time constant 8 in this problem.
  float* out = (float*)d_out;
  hipMemsetAsync(out, 0, sizeof(float), stream);
  t2l2_kernel<<<dim3(NROWS), dim3(BLK), 0, stream>>>(pred, target, out);
}